// Round 7
// baseline (207.448 us; speedup 1.0000x reference)
//
#include <hip/hip_runtime.h>

#define H_ 160
#define W_ 160
#define HW_ (H_ * W_)
#define NPIX (8 * HW_)   // 204800 pixels

// ============================================================================
// R17: two independent changes, separately attributable:
//  (1) nhwc_bf16: stores vectorized 4B x16 -> 16B x4 (u32x4). The old pattern
//      had each store inst touching 64 cache lines (128B lane stride); 4x
//      fewer insts. Identical values+layout. Diagnoses the constant ~75us
//      non-dcn gap (nhwc vs launch overhead).
//  (2) dcn_fused: __launch_bounds__ (256,4)->(256,5): 20 waves/CU
//      (LDS 28160*5=140.8KB fits; VGPR 64 <= 102 cap). More TLP for the
//      distributed latency stalls (VALU 40%, occ 30%, all pipes idle).
// Everything else verbatim R16 (fences kept: noise-neutral, theoretically
// sound). Numerics bit-identical to R14/R16 (absmax 0.03125).
// Layouts (verified m74/m101 + R9 pass): A[m=lane&31][k=(lane>>5)*8+j],
// B[n=lane&31][k=...], D: col n=lane&31, row=(reg&3)+8*(reg>>2)+4*(lane>>5).
// ============================================================================

typedef __attribute__((ext_vector_type(8)))  short  short8;   // 8 bf16
typedef __attribute__((ext_vector_type(4)))  float  f32x4;
typedef __attribute__((ext_vector_type(2)))  float  f32x2;
typedef __attribute__((ext_vector_type(16))) float  f32x16;
typedef __attribute__((ext_vector_type(4)))  unsigned u32x4;

__device__ __forceinline__ unsigned short bf16_rne(float f) {
    unsigned u = __float_as_uint(f);
    u += 0x7fffu + ((u >> 16) & 1u);
    return (unsigned short)(u >> 16);
}
__device__ __forceinline__ unsigned pack2_bf16(float a, float b) {
    unsigned ua = __float_as_uint(a); ua += 0x7fffu + ((ua >> 16) & 1u);
    unsigned ub = __float_as_uint(b); ub += 0x7fffu + ((ub >> 16) & 1u);
    return (ua >> 16) | (ub & 0xffff0000u);
}
__device__ __forceinline__ f32x2 up2(unsigned u) {
    f32x2 r;
    r.x = __uint_as_float(u << 16);
    r.y = __uint_as_float(u & 0xffff0000u);
    return r;
}

// ---- x (B,32,H,W) fp32 -> xT (B,H,W,32) bf16; 16B stores -------------------
__global__ __launch_bounds__(256) void nhwc_bf16(
    const float* __restrict__ x, unsigned short* __restrict__ xT)
{
    const int pix = blockIdx.x * 256 + threadIdx.x;
    const int p = pix % HW_;
    const int b = pix / HW_;
    const float* __restrict__ src = x + (size_t)b * 32 * HW_ + p;
    u32x4* __restrict__ dst = (u32x4*)(xT + (size_t)pix * 32);
    #pragma unroll
    for (int q = 0; q < 4; ++q) {
        u32x4 v;
        v.x = pack2_bf16(src[(8 * q + 0) * HW_], src[(8 * q + 1) * HW_]);
        v.y = pack2_bf16(src[(8 * q + 2) * HW_], src[(8 * q + 3) * HW_]);
        v.z = pack2_bf16(src[(8 * q + 4) * HW_], src[(8 * q + 5) * HW_]);
        v.w = pack2_bf16(src[(8 * q + 6) * HW_], src[(8 * q + 7) * HW_]);
        dst[q] = v;
    }
}

// ---- fused: offset conv + bilinear sampling + dcn GEMM + ReLU --------------
__global__ __launch_bounds__(256, 5) void dcn_fused(
    const unsigned short* __restrict__ xT,   // (8,160,160,32) bf16
    const float* __restrict__ w_off,         // (18, 32, 3, 3)
    const float* __restrict__ b_off,         // (18,)
    const float* __restrict__ w_dcn,         // (32, 32, 3, 3)
    float* __restrict__ out)                 // (8, 32, 160, 160)
{
    // ONE weight-frag buffer, time-shared: wo in stage 1, wd in stage 2.
    __shared__ __align__(16) unsigned short wsh[9 * 2 * 64 * 8];  // 18,432 B
    __shared__ float offl[4 * 18 * 33];   // per-wave offset transpose, pad 33
    __shared__ float bl[32];
    const int tid = threadIdx.x;

    // stage wo (R11 staging loop, target = wsh)
    for (int d = tid; d < 9 * 1024; d += 256) {
        const int tap = d >> 10, r = d & 1023, j = r >> 5, c = r & 31;
        const int s = c >> 4, kg = (c >> 3) & 1;
        const int unit = (tap * 2 + s) * 64 + j + 32 * kg;
        wsh[unit * 8 + (c & 7)] = (j < 18) ? bf16_rne(w_off[(j * 32 + c) * 9 + tap])
                                           : (unsigned short)0;
    }
    if (tid < 32) bl[tid] = (tid < 18) ? b_off[tid] : 0.0f;
    __syncthreads();

    const int wave = tid >> 6, lane = tid & 63;
    const int n = lane & 31;          // pixel (A-row m) == out channel (D-col)
    const int hh = lane >> 5;         // k-group
    // XCD-chunked swizzle: XCD k owns batch k (200 blocks = one image = 1.6MB
    // xT -> L2-resident per XCD). Bijective since 1600 % 8 == 0.
    const int bid = (blockIdx.x & 7) * 200 + (blockIdx.x >> 3);
    const int pixbase = bid * 128 + wave * 32;
    const int pix = pixbase + n;
    const int w = pix % W_, h = (pix / W_) % H_, b = pix / HW_;
    const unsigned short* __restrict__ xb = xT + (size_t)b * HW_ * 32 + hh * 8;

    // ------- stage 1: offset conv GEMM, all 18 gathers issued up front -----
    {
        f32x16 acc = {};
        const u32x4 z4 = {0u, 0u, 0u, 0u};
        u32x4 lr[18];      // raw gathers (static indices under full unroll)
        int   va[9];       // per-tap validity
        #pragma unroll
        for (int tap = 0; tap < 9; ++tap) {
            const int yy = h - 1 + tap / 3;
            const int xx = w - 1 + tap % 3;
            va[tap] = (yy >= 0) && (yy < H_) && (xx >= 0) && (xx < W_);
            const int idx = min(max(yy, 0), H_ - 1) * W_ + min(max(xx, 0), W_ - 1);
            const unsigned short* __restrict__ px_ = xb + (size_t)idx * 32;
            lr[2 * tap]     = *(const u32x4*)(px_);
            lr[2 * tap + 1] = *(const u32x4*)(px_ + 16);
        }
        __builtin_amdgcn_sched_barrier(0);   // all 18 loads issue before use
        #pragma unroll
        for (int tap = 0; tap < 9; ++tap) {
            const u32x4 l0 = va[tap] ? lr[2 * tap]     : z4;
            const u32x4 l1 = va[tap] ? lr[2 * tap + 1] : z4;
            const short8 a0 = __builtin_bit_cast(short8, l0);
            const short8 a1 = __builtin_bit_cast(short8, l1);
            const short8 b0 = *(const short8*)(wsh + ((tap * 2 + 0) * 64 + lane) * 8);
            const short8 b1 = *(const short8*)(wsh + ((tap * 2 + 1) * 64 + lane) * 8);
            acc = __builtin_amdgcn_mfma_f32_32x32x16_bf16(a0, b0, acc, 0, 0, 0);
            acc = __builtin_amdgcn_mfma_f32_32x32x16_bf16(a1, b1, acc, 0, 0, 0);
        }
        // D-layout -> per-wave LDS transpose: [j(18)][pix(32)], row pad 33
        float* __restrict__ owp = offl + wave * 594;
        if (n < 18) {
            const float bia = bl[n];
            #pragma unroll
            for (int r = 0; r < 16; ++r) {
                const int prow = (r & 3) + 8 * (r >> 2) + 4 * hh;
                owp[n * 33 + prow] = acc[r] + bia;
            }
        }
    }
    __syncthreads();   // stage-1 reads of wsh done everywhere; offl visible

    // re-stage: wd into the SAME buffer
    for (int d = tid; d < 9 * 1024; d += 256) {
        const int tap = d >> 10, r = d & 1023, j = r >> 5, c = r & 31;
        const int s = c >> 4, kg = (c >> 3) & 1;
        const int unit = (tap * 2 + s) * 64 + j + 32 * kg;
        wsh[unit * 8 + (c & 7)] = bf16_rne(w_dcn[(j * 32 + c) * 9 + tap]);
    }
    __syncthreads();   // wd visible

    // ------ stage 2: bilinear sampling + dcn GEMM, depth-1 pipelined -------
    const float* __restrict__ ow = offl + wave * 594;
    f32x16 acc = {};

    // double-buffered pipeline state (indices static under full unroll)
    u32x4 gA0[2], gA1[2], gB0[2], gB1[2], gC0[2], gC1[2], gD0[2], gD1[2];
    f32x4 cw[2];   // {w00, w01, w10, w11}

    #define PREP(t, s) do { \
        const float dy = ow[(2 * (t)) * 33 + n]; \
        const float dx = ow[(2 * (t) + 1) * 33 + n]; \
        const float py = (float)(h - 1 + (t) / 3) + dy; \
        const float px = (float)(w - 1 + (t) % 3) + dx; \
        const float fy0 = floorf(py), fx0 = floorf(px); \
        const float wy1 = py - fy0, wx1 = px - fx0; \
        const float wy0 = 1.0f - wy1, wx0 = 1.0f - wx1; \
        const int y0 = (int)fy0, x0 = (int)fx0; \
        const bool vy0 = (y0 >= 0) && (y0 < H_); \
        const bool vy1 = (y0 + 1 >= 0) && (y0 + 1 < H_); \
        const bool vx0 = (x0 >= 0) && (x0 < W_); \
        const bool vx1 = (x0 + 1 >= 0) && (x0 + 1 < W_); \
        cw[s].x = (vy0 && vx0) ? wy0 * wx0 : 0.0f; \
        cw[s].y = (vy0 && vx1) ? wy0 * wx1 : 0.0f; \
        cw[s].z = (vy1 && vx0) ? wy1 * wx0 : 0.0f; \
        cw[s].w = (vy1 && vx1) ? wy1 * wx1 : 0.0f; \
        const int yc0 = min(max(y0, 0), H_ - 1), yc1 = min(max(y0 + 1, 0), H_ - 1); \
        const int xc0 = min(max(x0, 0), W_ - 1), xc1 = min(max(x0 + 1, 0), W_ - 1); \
        const unsigned short* pA = xb + (size_t)(yc0 * W_ + xc0) * 32; \
        const unsigned short* pB = xb + (size_t)(yc0 * W_ + xc1) * 32; \
        const unsigned short* pC = xb + (size_t)(yc1 * W_ + xc0) * 32; \
        const unsigned short* pD = xb + (size_t)(yc1 * W_ + xc1) * 32; \
        gA0[s] = *(const u32x4*)(pA);  gA1[s] = *(const u32x4*)(pA + 16); \
        gB0[s] = *(const u32x4*)(pB);  gB1[s] = *(const u32x4*)(pB + 16); \
        gC0[s] = *(const u32x4*)(pC);  gC1[s] = *(const u32x4*)(pC + 16); \
        gD0[s] = *(const u32x4*)(pD);  gD1[s] = *(const u32x4*)(pD + 16); \
    } while (0)

    PREP(0, 0);
    #pragma unroll
    for (int tap = 0; tap < 9; ++tap) {
        const int cur = tap & 1, nxt = cur ^ 1;
        if (tap < 8) PREP(tap + 1, nxt);   // issue next tap's 8 gathers
        __builtin_amdgcn_sched_barrier(0); // pin: loads stay above combine

        const float w00 = cw[cur].x, w01 = cw[cur].y;
        const float w10 = cw[cur].z, w11 = cw[cur].w;
        // R9-verified packed-fp32 bilinear combine
        #define COMB(a, bb, cc, dd) ({ \
            const f32x2 v = up2(a) * w00 + up2(bb) * w01 + up2(cc) * w10 + up2(dd) * w11; \
            pack2_bf16(v.x, v.y); })
        u32x4 av0, av1;
        av0.x = COMB(gA0[cur].x, gB0[cur].x, gC0[cur].x, gD0[cur].x);
        av0.y = COMB(gA0[cur].y, gB0[cur].y, gC0[cur].y, gD0[cur].y);
        av0.z = COMB(gA0[cur].z, gB0[cur].z, gC0[cur].z, gD0[cur].z);
        av0.w = COMB(gA0[cur].w, gB0[cur].w, gC0[cur].w, gD0[cur].w);
        av1.x = COMB(gA1[cur].x, gB1[cur].x, gC1[cur].x, gD1[cur].x);
        av1.y = COMB(gA1[cur].y, gB1[cur].y, gC1[cur].y, gD1[cur].y);
        av1.z = COMB(gA1[cur].z, gB1[cur].z, gC1[cur].z, gD1[cur].z);
        av1.w = COMB(gA1[cur].w, gB1[cur].w, gC1[cur].w, gD1[cur].w);
        #undef COMB

        const short8 a0 = __builtin_bit_cast(short8, av0);
        const short8 a1 = __builtin_bit_cast(short8, av1);
        const short8 b0 = *(const short8*)(wsh + ((tap * 2 + 0) * 64 + lane) * 8);
        const short8 b1 = *(const short8*)(wsh + ((tap * 2 + 1) * 64 + lane) * 8);
        acc = __builtin_amdgcn_mfma_f32_32x32x16_bf16(a0, b0, acc, 0, 0, 0);
        acc = __builtin_amdgcn_mfma_f32_32x32x16_bf16(a1, b1, acc, 0, 0, 0);
    }
    #undef PREP

    // D: col o = n; rows = pixels pixbase + g*8 + 4*hh + i
    float* __restrict__ ob = out + (size_t)b * 32 * HW_ + (size_t)n * HW_
                           + (pixbase - b * HW_) + 4 * hh;
    #pragma unroll
    for (int g = 0; g < 4; ++g) {
        f32x4 r;
        #pragma unroll
        for (int i = 0; i < 4; ++i) r[i] = fmaxf(acc[g * 4 + i], 0.0f);
        *(f32x4*)(ob + g * 8) = r;
    }
}

extern "C" void kernel_launch(void* const* d_in, const int* in_sizes, int n_in,
                              void* d_out, int out_size, void* d_ws, size_t ws_size,
                              hipStream_t stream) {
    const float* x     = (const float*)d_in[0];
    const float* w_off = (const float*)d_in[1];
    const float* b_off = (const float*)d_in[2];
    const float* w_dcn = (const float*)d_in[3];
    float* out = (float*)d_out;

    unsigned short* xT = (unsigned short*)d_ws;   // 13.1 MB bf16 NHWC (R11 footprint)

    nhwc_bf16<<<800, 256, 0, stream>>>(x, xT);
    dcn_fused<<<1600, 256, 0, stream>>>(xT, w_off, b_off, w_dcn, out);
}

// Round 8
// 138.138 us; speedup vs baseline: 1.5017x; 1.5017x over previous
//
#include <hip/hip_runtime.h>

#define H_ 160
#define W_ 160
#define HW_ (H_ * W_)
#define NPIX (8 * HW_)   // 204800 pixels

// ============================================================================
// R18: revert R17's spill, then cut VALU + staging TA cost.
//  - (256,5) -> (256,4): R17's WRITE 145MB/FETCH 44MB = pipeline spilled to
//    scratch at 48 VGPR. R16 config (VGPR 64, WRITE 25.6MB) restored.
//  - v_cvt_pk_bf16_f32 replaces pack2_bf16 (8 insts -> 1, RNE-identical).
//    R12's failure re-attributed to OOB workspace writes (woG/wdG past
//    ws_size), not cvt_pk (learn_hip m214v22/m240 refcheck'd). Weights stay
//    in LDS here - cvt_pk is the single numerics-adjacent variable.
//  - weight staging: old d-loop loads w[(j*32+c)*9+tap] (36B lane stride,
//    ~36 cache lines per load inst, 72 insts/wave of TA serialization).
//    New: zero wsh (16B stores) -> barrier -> flat-coalesced w[f] loads
//    (f = tid+k*256, lane-consecutive) + decode j=f/288,c=(f%288)/9,tap=f%9
//    -> scatter ds_write. Identical final wsh contents.
// Everything else verbatim R16: XCD-chunked swizzle, LDS time-share, fences,
// bf16 MFMA layouts, f32x2 packed combine, C-write.
// Layouts (verified m74/m101 + R9 pass): A[m=lane&31][k=(lane>>5)*8+j],
// B[n=lane&31][k=...], D: col n=lane&31, row=(reg&3)+8*(reg>>2)+4*(lane>>5).
// ============================================================================

typedef __attribute__((ext_vector_type(8)))  short  short8;   // 8 bf16
typedef __attribute__((ext_vector_type(4)))  float  f32x4;
typedef __attribute__((ext_vector_type(2)))  float  f32x2;
typedef __attribute__((ext_vector_type(16))) float  f32x16;
typedef __attribute__((ext_vector_type(4)))  unsigned u32x4;

__device__ __forceinline__ unsigned short bf16_rne(float f) {
    unsigned u = __float_as_uint(f);
    u += 0x7fffu + ((u >> 16) & 1u);
    return (unsigned short)(u >> 16);
}
// v_cvt_pk_bf16_f32: dst.lo = bf16(a), dst.hi = bf16(b); RNE — bit-identical
// to pack2_bf16 for non-NaN inputs, 1 VALU op instead of ~8.
__device__ __forceinline__ unsigned cvt_pk_bf16(float a, float b) {
    unsigned r;
    asm("v_cvt_pk_bf16_f32 %0, %1, %2" : "=v"(r) : "v"(a), "v"(b));
    return r;
}
__device__ __forceinline__ f32x2 up2(unsigned u) {
    f32x2 r;
    r.x = __uint_as_float(u << 16);
    r.y = __uint_as_float(u & 0xffff0000u);
    return r;
}

// ---- x (B,32,H,W) fp32 -> xT (B,H,W,32) bf16; 16B stores -------------------
__global__ __launch_bounds__(256) void nhwc_bf16(
    const float* __restrict__ x, unsigned short* __restrict__ xT)
{
    const int pix = blockIdx.x * 256 + threadIdx.x;
    const int p = pix % HW_;
    const int b = pix / HW_;
    const float* __restrict__ src = x + (size_t)b * 32 * HW_ + p;
    u32x4* __restrict__ dst = (u32x4*)(xT + (size_t)pix * 32);
    #pragma unroll
    for (int q = 0; q < 4; ++q) {
        u32x4 v;
        v.x = cvt_pk_bf16(src[(8 * q + 0) * HW_], src[(8 * q + 1) * HW_]);
        v.y = cvt_pk_bf16(src[(8 * q + 2) * HW_], src[(8 * q + 3) * HW_]);
        v.z = cvt_pk_bf16(src[(8 * q + 4) * HW_], src[(8 * q + 5) * HW_]);
        v.w = cvt_pk_bf16(src[(8 * q + 6) * HW_], src[(8 * q + 7) * HW_]);
        dst[q] = v;
    }
}

// scatter-destination for flat weight index f (f = j*288 + c*9 + tap):
// identical mapping to the old d-loop's (tap,j,c) -> wsh slot.
__device__ __forceinline__ int wsh_slot(unsigned f) {
    const unsigned j   = f / 288u;
    const unsigned rem = f - j * 288u;
    const unsigned c   = rem / 9u;
    const unsigned tap = rem - c * 9u;
    const unsigned unit = (tap * 2u + (c >> 4)) * 64u + j + 32u * ((c >> 3) & 1u);
    return (int)(unit * 8u + (c & 7u));
}

// ---- fused: offset conv + bilinear sampling + dcn GEMM + ReLU --------------
__global__ __launch_bounds__(256, 4) void dcn_fused(
    const unsigned short* __restrict__ xT,   // (8,160,160,32) bf16
    const float* __restrict__ w_off,         // (18, 32, 3, 3) = 5184 floats
    const float* __restrict__ b_off,         // (18,)
    const float* __restrict__ w_dcn,         // (32, 32, 3, 3) = 9216 floats
    float* __restrict__ out)                 // (8, 32, 160, 160)
{
    // ONE weight-frag buffer, time-shared: wo in stage 1, wd in stage 2.
    __shared__ __align__(16) unsigned short wsh[9 * 2 * 64 * 8];  // 18,432 B
    __shared__ float offl[4 * 18 * 33];   // per-wave offset transpose, pad 33
    __shared__ float bl[32];
    const int tid = threadIdx.x;

    // ---- zero wsh (j>=18 slots must be 0), vector stores ----
    {
        u32x4* wz = (u32x4*)wsh;
        const u32x4 z = {0u, 0u, 0u, 0u};
        for (int q = tid; q < 1152; q += 256) wz[q] = z;   // 1152*16B = 18432B
    }
    if (tid < 32) bl[tid] = (tid < 18) ? b_off[tid] : 0.0f;
    __syncthreads();

    // ---- stage wo: flat-coalesced loads + scatter (5184 floats) ----
    for (unsigned f = tid; f < 5184u; f += 256u)
        wsh[wsh_slot(f)] = bf16_rne(w_off[f]);
    __syncthreads();

    const int wave = tid >> 6, lane = tid & 63;
    const int n = lane & 31;          // pixel (A-row m) == out channel (D-col)
    const int hh = lane >> 5;         // k-group
    // XCD-chunked swizzle: XCD k owns batch k (200 blocks = one image = 1.6MB
    // xT -> L2-resident per XCD). Bijective since 1600 % 8 == 0.
    const int bid = (blockIdx.x & 7) * 200 + (blockIdx.x >> 3);
    const int pixbase = bid * 128 + wave * 32;
    const int pix = pixbase + n;
    const int w = pix % W_, h = (pix / W_) % H_, b = pix / HW_;
    const unsigned short* __restrict__ xb = xT + (size_t)b * HW_ * 32 + hh * 8;

    // ------- stage 1: offset conv GEMM, all 18 gathers issued up front -----
    {
        f32x16 acc = {};
        const u32x4 z4 = {0u, 0u, 0u, 0u};
        u32x4 lr[18];      // raw gathers (static indices under full unroll)
        int   va[9];       // per-tap validity
        #pragma unroll
        for (int tap = 0; tap < 9; ++tap) {
            const int yy = h - 1 + tap / 3;
            const int xx = w - 1 + tap % 3;
            va[tap] = (yy >= 0) && (yy < H_) && (xx >= 0) && (xx < W_);
            const int idx = min(max(yy, 0), H_ - 1) * W_ + min(max(xx, 0), W_ - 1);
            const unsigned short* __restrict__ px_ = xb + (size_t)idx * 32;
            lr[2 * tap]     = *(const u32x4*)(px_);
            lr[2 * tap + 1] = *(const u32x4*)(px_ + 16);
        }
        __builtin_amdgcn_sched_barrier(0);   // all 18 loads issue before use
        #pragma unroll
        for (int tap = 0; tap < 9; ++tap) {
            const u32x4 l0 = va[tap] ? lr[2 * tap]     : z4;
            const u32x4 l1 = va[tap] ? lr[2 * tap + 1] : z4;
            const short8 a0 = __builtin_bit_cast(short8, l0);
            const short8 a1 = __builtin_bit_cast(short8, l1);
            const short8 b0 = *(const short8*)(wsh + ((tap * 2 + 0) * 64 + lane) * 8);
            const short8 b1 = *(const short8*)(wsh + ((tap * 2 + 1) * 64 + lane) * 8);
            acc = __builtin_amdgcn_mfma_f32_32x32x16_bf16(a0, b0, acc, 0, 0, 0);
            acc = __builtin_amdgcn_mfma_f32_32x32x16_bf16(a1, b1, acc, 0, 0, 0);
        }
        // D-layout -> per-wave LDS transpose: [j(18)][pix(32)], row pad 33
        float* __restrict__ owp = offl + wave * 594;
        if (n < 18) {
            const float bia = bl[n];
            #pragma unroll
            for (int r = 0; r < 16; ++r) {
                const int prow = (r & 3) + 8 * (r >> 2) + 4 * hh;
                owp[n * 33 + prow] = acc[r] + bia;
            }
        }
    }
    __syncthreads();   // stage-1 reads of wsh done everywhere; offl visible

    // ---- re-stage wd: flat-coalesced loads + scatter (9216 floats, all
    //      slots covered -> no zero-fill needed) ----
    for (unsigned f = tid; f < 9216u; f += 256u)
        wsh[wsh_slot(f)] = bf16_rne(w_dcn[f]);
    __syncthreads();   // wd visible

    // ------ stage 2: bilinear sampling + dcn GEMM, depth-1 pipelined -------
    const float* __restrict__ ow = offl + wave * 594;
    f32x16 acc = {};

    // double-buffered pipeline state (indices static under full unroll)
    u32x4 gA0[2], gA1[2], gB0[2], gB1[2], gC0[2], gC1[2], gD0[2], gD1[2];
    f32x4 cw[2];   // {w00, w01, w10, w11}

    #define PREP(t, s) do { \
        const float dy = ow[(2 * (t)) * 33 + n]; \
        const float dx = ow[(2 * (t) + 1) * 33 + n]; \
        const float py = (float)(h - 1 + (t) / 3) + dy; \
        const float px = (float)(w - 1 + (t) % 3) + dx; \
        const float fy0 = floorf(py), fx0 = floorf(px); \
        const float wy1 = py - fy0, wx1 = px - fx0; \
        const float wy0 = 1.0f - wy1, wx0 = 1.0f - wx1; \
        const int y0 = (int)fy0, x0 = (int)fx0; \
        const bool vy0 = (y0 >= 0) && (y0 < H_); \
        const bool vy1 = (y0 + 1 >= 0) && (y0 + 1 < H_); \
        const bool vx0 = (x0 >= 0) && (x0 < W_); \
        const bool vx1 = (x0 + 1 >= 0) && (x0 + 1 < W_); \
        cw[s].x = (vy0 && vx0) ? wy0 * wx0 : 0.0f; \
        cw[s].y = (vy0 && vx1) ? wy0 * wx1 : 0.0f; \
        cw[s].z = (vy1 && vx0) ? wy1 * wx0 : 0.0f; \
        cw[s].w = (vy1 && vx1) ? wy1 * wx1 : 0.0f; \
        const int yc0 = min(max(y0, 0), H_ - 1), yc1 = min(max(y0 + 1, 0), H_ - 1); \
        const int xc0 = min(max(x0, 0), W_ - 1), xc1 = min(max(x0 + 1, 0), W_ - 1); \
        const unsigned short* pA = xb + (size_t)(yc0 * W_ + xc0) * 32; \
        const unsigned short* pB = xb + (size_t)(yc0 * W_ + xc1) * 32; \
        const unsigned short* pC = xb + (size_t)(yc1 * W_ + xc0) * 32; \
        const unsigned short* pD = xb + (size_t)(yc1 * W_ + xc1) * 32; \
        gA0[s] = *(const u32x4*)(pA);  gA1[s] = *(const u32x4*)(pA + 16); \
        gB0[s] = *(const u32x4*)(pB);  gB1[s] = *(const u32x4*)(pB + 16); \
        gC0[s] = *(const u32x4*)(pC);  gC1[s] = *(const u32x4*)(pC + 16); \
        gD0[s] = *(const u32x4*)(pD);  gD1[s] = *(const u32x4*)(pD + 16); \
    } while (0)

    PREP(0, 0);
    #pragma unroll
    for (int tap = 0; tap < 9; ++tap) {
        const int cur = tap & 1, nxt = cur ^ 1;
        if (tap < 8) PREP(tap + 1, nxt);   // issue next tap's 8 gathers
        __builtin_amdgcn_sched_barrier(0); // pin: loads stay above combine

        const float w00 = cw[cur].x, w01 = cw[cur].y;
        const float w10 = cw[cur].z, w11 = cw[cur].w;
        // packed-fp32 bilinear combine + 1-op RNE bf16 pack
        #define COMB(a, bb, cc, dd) ({ \
            const f32x2 v = up2(a) * w00 + up2(bb) * w01 + up2(cc) * w10 + up2(dd) * w11; \
            cvt_pk_bf16(v.x, v.y); })
        u32x4 av0, av1;
        av0.x = COMB(gA0[cur].x, gB0[cur].x, gC0[cur].x, gD0[cur].x);
        av0.y = COMB(gA0[cur].y, gB0[cur].y, gC0[cur].y, gD0[cur].y);
        av0.z = COMB(gA0[cur].z, gB0[cur].z, gC0[cur].z, gD0[cur].z);
        av0.w = COMB(gA0[cur].w, gB0[cur].w, gC0[cur].w, gD0[cur].w);
        av1.x = COMB(gA1[cur].x, gB1[cur].x, gC1[cur].x, gD1[cur].x);
        av1.y = COMB(gA1[cur].y, gB1[cur].y, gC1[cur].y, gD1[cur].y);
        av1.z = COMB(gA1[cur].z, gB1[cur].z, gC1[cur].z, gD1[cur].z);
        av1.w = COMB(gA1[cur].w, gB1[cur].w, gC1[cur].w, gD1[cur].w);
        #undef COMB

        const short8 a0 = __builtin_bit_cast(short8, av0);
        const short8 a1 = __builtin_bit_cast(short8, av1);
        const short8 b0 = *(const short8*)(wsh + ((tap * 2 + 0) * 64 + lane) * 8);
        const short8 b1 = *(const short8*)(wsh + ((tap * 2 + 1) * 64 + lane) * 8);
        acc = __builtin_amdgcn_mfma_f32_32x32x16_bf16(a0, b0, acc, 0, 0, 0);
        acc = __builtin_amdgcn_mfma_f32_32x32x16_bf16(a1, b1, acc, 0, 0, 0);
    }
    #undef PREP

    // D: col o = n; rows = pixels pixbase + g*8 + 4*hh + i
    float* __restrict__ ob = out + (size_t)b * 32 * HW_ + (size_t)n * HW_
                           + (pixbase - b * HW_) + 4 * hh;
    #pragma unroll
    for (int g = 0; g < 4; ++g) {
        f32x4 r;
        #pragma unroll
        for (int i = 0; i < 4; ++i) r[i] = fmaxf(acc[g * 4 + i], 0.0f);
        *(f32x4*)(ob + g * 8) = r;
    }
}

extern "C" void kernel_launch(void* const* d_in, const int* in_sizes, int n_in,
                              void* d_out, int out_size, void* d_ws, size_t ws_size,
                              hipStream_t stream) {
    const float* x     = (const float*)d_in[0];
    const float* w_off = (const float*)d_in[1];
    const float* b_off = (const float*)d_in[2];
    const float* w_dcn = (const float*)d_in[3];
    float* out = (float*)d_out;

    unsigned short* xT = (unsigned short*)d_ws;   // 13.1 MB bf16 NHWC (R11 footprint)

    nhwc_bf16<<<800, 256, 0, stream>>>(x, xT);
    dcn_fused<<<1600, 256, 0, stream>>>(xT, w_off, b_off, w_dcn, out);
}